// Round 10
// baseline (143.583 us; speedup 1.0000x reference)
//
#include <hip/hip_runtime.h>

#define S_LEN 2048
#define NH 16
#define HD 64
#define DM 1024
#define MTOT 4096

// q pre-scale: 1/sqrt(64) * log2(e), so attn softmax is exp2(q.k)
#define QSCALE 0.18033688011112042f

typedef short bf16x8 __attribute__((ext_vector_type(8)));
typedef float f32x4 __attribute__((ext_vector_type(4)));
typedef unsigned short u16x8 __attribute__((ext_vector_type(8)));

__device__ __forceinline__ unsigned short f2bf(float f) {
  unsigned int u = __builtin_bit_cast(unsigned int, f);
  u += 0x7fffu + ((u >> 16) & 1u);
  return (unsigned short)(u >> 16);
}
// round-half-up, 2 ops; bias cancels in softmax normalization
__device__ __forceinline__ unsigned short f2bf_fast(float f) {
  unsigned int u = __builtin_bit_cast(unsigned int, f);
  return (unsigned short)((u + 0x8000u) >> 16);
}

__device__ __forceinline__ void async_copy16(const void* g, void* l) {
  __builtin_amdgcn_global_load_lds(
      (const __attribute__((address_space(1))) unsigned int*)g,
      (__attribute__((address_space(3))) unsigned int*)l, 16, 0, 0);
}

// ---------------- fp32 -> bf16 convert ----------------
__global__ void cvt_bf16_kernel(const float* __restrict__ src,
                                unsigned short* __restrict__ dst, int n) {
  int i = (blockIdx.x * 256 + threadIdx.x) * 8;
  if (i >= n) return;
  const float4* s = (const float4*)(src + i);
  float4 v0 = s[0], v1 = s[1];
  u16x8 o;
  o[0] = f2bf(v0.x); o[1] = f2bf(v0.y); o[2] = f2bf(v0.z); o[3] = f2bf(v0.w);
  o[4] = f2bf(v1.x); o[5] = f2bf(v1.y); o[6] = f2bf(v1.z); o[7] = f2bf(v1.w);
  *(u16x8*)(dst + i) = o;
}

// 4 weight matrices in one launch
__global__ void cvt_w_kernel(const float* __restrict__ w0, const float* __restrict__ w1,
                             const float* __restrict__ w2, const float* __restrict__ w3,
                             unsigned short* __restrict__ dst) {
  int z = blockIdx.y;
  const float* src = (z == 0) ? w0 : (z == 1) ? w1 : (z == 2) ? w2 : w3;
  int i = (blockIdx.x * 256 + threadIdx.x) * 8;
  const float4* s = (const float4*)(src + i);
  float4 v0 = s[0], v1 = s[1];
  u16x8 o;
  o[0] = f2bf(v0.x); o[1] = f2bf(v0.y); o[2] = f2bf(v0.z); o[3] = f2bf(v0.w);
  o[4] = f2bf(v1.x); o[5] = f2bf(v1.y); o[6] = f2bf(v1.z); o[7] = f2bf(v1.w);
  *(u16x8*)(dst + (size_t)z * DM * DM + i) = o;
}

// ---------------- RoPE cos/sin table ----------------
__global__ void sincos_tab_kernel(const int* __restrict__ pos, float2* __restrict__ tab) {
  int idx = blockIdx.x * 256 + threadIdx.x;  // 0 .. 65535
  int s = idx >> 5, i = idx & 31;
  float fr = expf(-(float)i * 0.28782313662425574f);  // ln(10000)/32
  float ang = (float)pos[s] * fr;
  float sn, cs;
  sincosf(ang, &sn, &cs);
  tab[idx] = make_float2(cs, sn);
}

// ---------------- shared GEMM core: C = A(MxK) @ Bt(NxK)^T, 128x128 tile, BK=32 ----------------
// 3-stage pipeline with COUNTED vmcnt (T4): loads stay in flight across raw s_barriers.
//   iter kt: vmcnt(8) [only tile kt landed] -> bar -> compute -> bar -> stage(kt+3)
// LDS layout packs 2 M-rows per 128B LDS row, slot-swizzled:
//   logical (r, g16B) at byte (r>>1)*128 + ((((r&1)*4+g) ^ ((r>>1)&7))<<4)  -- conflict-free reads.
// Staging writes linearly (global_load_lds constraint); source address carries the inverse permutation.
__device__ __forceinline__ void gemm_core(const unsigned short* __restrict__ A,
                                          const unsigned short* __restrict__ Bt,
                                          int m0, int n0, int K,
                                          char* a_lds, char* b_lds,  // each 3 x 8KB
                                          f32x4 (&acc)[4][4]) {
  const int tid = threadIdx.x;
  const int w = tid >> 6, l = tid & 63;
  const int wr = w >> 1, wc = w & 1;
  const int c = l & 15, g = l >> 4;
  const size_t rs = (size_t)K * 2;  // row stride bytes

  // staging source (lane-constant): lane l, instr i covers logical row
  // r = 64*i + 16*w + 2*(l>>3) + (u>>2), granule u&3, with u = (l&7)^(l>>3).
  const int u = (l & 7) ^ (l >> 3);
  const int rbl = 16 * w + 2 * (l >> 3) + (u >> 2);
  const char* sA0 = (const char*)A + ((size_t)m0 + rbl) * rs + (u & 3) * 16;
  const char* sA1 = sA0 + 64 * rs;
  const char* sB0 = (const char*)Bt + ((size_t)n0 + rbl) * rs + (u & 3) * 16;
  const char* sB1 = sB0 + 64 * rs;
  char* dA = a_lds + w * 1024 + l * 16;
  char* dB = b_lds + w * 1024 + l * 16;

  // per-lane read addresses within a tile buffer
  int raddrA[4], raddrB[4];
#pragma unroll
  for (int mi = 0; mi < 4; ++mi) {
    int r = wr * 64 + mi * 16 + c;
    raddrA[mi] = (r >> 1) * 128 + (((((r & 1) << 2) + g) ^ ((r >> 1) & 7)) << 4);
    int rb = wc * 64 + mi * 16 + c;
    raddrB[mi] = (rb >> 1) * 128 + (((((rb & 1) << 2) + g) ^ ((rb >> 1) & 7)) << 4);
  }

  auto stage = [&](int buf, int kt) {
    const size_t ko = (size_t)kt * 64;
    const int off = buf * 8192;
    async_copy16(sA0 + ko, dA + off);
    async_copy16(sA1 + ko, dA + off + 4096);
    async_copy16(sB0 + ko, dB + off);
    async_copy16(sB1 + ko, dB + off + 4096);
  };

  auto compute = [&](int buf) {
    const char* al = a_lds + buf * 8192;
    const char* bl = b_lds + buf * 8192;
    bf16x8 af[4], bfv[4];
#pragma unroll
    for (int mi = 0; mi < 4; ++mi) af[mi] = *(const bf16x8*)(al + raddrA[mi]);
#pragma unroll
    for (int ni = 0; ni < 4; ++ni) bfv[ni] = *(const bf16x8*)(bl + raddrB[ni]);
    __builtin_amdgcn_s_setprio(1);
#pragma unroll
    for (int mi = 0; mi < 4; ++mi)
#pragma unroll
      for (int ni = 0; ni < 4; ++ni)
        acc[mi][ni] = __builtin_amdgcn_mfma_f32_16x16x32_bf16(af[mi], bfv[ni], acc[mi][ni], 0, 0, 0);
    __builtin_amdgcn_s_setprio(0);
  };

  const int nsteps = K / 32;
  stage(0, 0);
  stage(1, 1);
  stage(2, 2);

  int buf = 0;
  for (int kt = 0; kt < nsteps; ++kt) {
    if (kt < nsteps - 2)
      asm volatile("s_waitcnt vmcnt(8)" ::: "memory");
    else if (kt == nsteps - 2)
      asm volatile("s_waitcnt vmcnt(4)" ::: "memory");
    else
      asm volatile("s_waitcnt vmcnt(0)" ::: "memory");
    __builtin_amdgcn_s_barrier();   // all waves' tile-kt loads landed
    compute(buf);
    if (kt + 3 < nsteps) {
      __builtin_amdgcn_s_barrier(); // everyone done reading buf before overwrite
      stage(buf, kt + 3);
    } else if (kt + 1 < nsteps) {
      __builtin_amdgcn_s_barrier();
    }
    buf = (buf == 2) ? 0 : buf + 1;
  }
}

// ---------------- QKV projection + fused RoPE: q,k -> [b,h,s,d]; v -> [b,h,d,s] ----------------
__global__ __launch_bounds__(256)
void gemm_qkv_kernel(const unsigned short* __restrict__ X,
                     const unsigned short* __restrict__ Wq,
                     const unsigned short* __restrict__ Wk,
                     const unsigned short* __restrict__ Wv,
                     const float2* __restrict__ tab,
                     unsigned short* __restrict__ Qb,
                     unsigned short* __restrict__ Kb,
                     unsigned short* __restrict__ Vt) {
  __shared__ char a_lds[3 * 8192];
  __shared__ char b_lds[3 * 8192];
  const int z = blockIdx.z;
  const unsigned short* Bt = (z == 0) ? Wq : (z == 1) ? Wk : Wv;
  const int m0 = blockIdx.x * 128, n0 = blockIdx.y * 128;

  f32x4 acc[4][4] = {};
  gemm_core(X, Bt, m0, n0, DM, a_lds, b_lds, acc);

  const int tid = threadIdx.x;
  const int w = tid >> 6, l = tid & 63;
  const int wr = w >> 1, wc = w & 1;
  const int c = l & 15, g = l >> 4;

  if (z == 2) {
#pragma unroll
    for (int mi = 0; mi < 4; ++mi)
#pragma unroll
      for (int ni = 0; ni < 4; ++ni)
#pragma unroll
        for (int r = 0; r < 4; ++r) {
          int row = m0 + wr * 64 + mi * 16 + 4 * g + r;  // token
          int col = n0 + wc * 64 + ni * 16 + c;          // feature
          int b = row >> 11, s = row & 2047;
          int h = col >> 6, d = col & 63;
          Vt[((size_t)(b * NH + h) * HD + d) * S_LEN + s] = f2bf(acc[mi][ni][r]);
        }
  } else {
    unsigned short* QK = z ? Kb : Qb;
    const float oscale = z ? 1.0f : QSCALE;
#pragma unroll
    for (int mi = 0; mi < 4; ++mi)
#pragma unroll
      for (int ni = 0; ni < 4; ++ni) {
        int col = n0 + wc * 64 + ni * 16 + c;
        int fi = (col >> 1) & 31;
        float sgn = (col & 1) ? 1.0f : -1.0f;
#pragma unroll
        for (int r = 0; r < 4; ++r) {
          int row = m0 + wr * 64 + mi * 16 + 4 * g + r;
          int b = row >> 11, s = row & 2047;
          float v = acc[mi][ni][r];
          float p = __shfl_xor(v, 1);
          float2 csn = tab[(s << 5) | fi];
          float vr = (v * csn.x + sgn * p * csn.y) * oscale;
          int h = col >> 6, d = col & 63;
          QK[((size_t)(b * NH + h) * S_LEN + s) * HD + d] = f2bf(vr);
        }
      }
  }
}

// ---------------- output projection: fp32 out ----------------
__global__ __launch_bounds__(256)
void gemm_out_kernel(const unsigned short* __restrict__ A,
                     const unsigned short* __restrict__ Wo,
                     float* __restrict__ out) {
  __shared__ char a_lds[3 * 8192];
  __shared__ char b_lds[3 * 8192];
  const int m0 = blockIdx.x * 128, n0 = blockIdx.y * 128;
  f32x4 acc[4][4] = {};
  gemm_core(A, Wo, m0, n0, DM, a_lds, b_lds, acc);

  const int tid = threadIdx.x;
  const int w = tid >> 6, l = tid & 63;
  const int wr = w >> 1, wc = w & 1;
  const int c = l & 15, g = l >> 4;
#pragma unroll
  for (int mi = 0; mi < 4; ++mi)
#pragma unroll
    for (int ni = 0; ni < 4; ++ni)
#pragma unroll
      for (int r = 0; r < 4; ++r) {
        int row = m0 + wr * 64 + mi * 16 + 4 * g + r;
        int col = n0 + wc * 64 + ni * 16 + c;
        out[(size_t)row * DM + col] = acc[mi][ni][r];
      }
}

// ---------------- causal flash attention: LDS-staged double-buffered K/V, kv-parity split ----------------
#define PART_STRIDE 4160  // 64*64 + 64 floats
__global__ __launch_bounds__(256, 4)
void attn_kernel(const unsigned short* __restrict__ Q,
                 const unsigned short* __restrict__ Kb,
                 const unsigned short* __restrict__ Vt,
                 float* __restrict__ part) {
  __shared__ char kbuf[2][8192];
  __shared__ char vbuf[2][8192];
  __shared__ unsigned short p_lds[4][16 * 64];
  const int tid = threadIdx.x;
  const int w = tid >> 6, l = tid & 63;
  const int g = l >> 4, c = l & 15;

  const unsigned int id = blockIdx.x;
  const int bh = id & 31;
  const int p = (id >> 5) & 1;
  const int qblk = 31 - (id >> 6);  // descending: long blocks first (LPT)
  const int q0 = qblk * 64;

  const size_t base = (size_t)bh * (S_LEN * HD);
  const char* Kc = (const char*)(Kb + base);
  const char* Vc = (const char*)(Vt + base);

  const int lr = l >> 3;
  const int jsw = ((l & 7) << 4) ^ (lr << 4);
  const int r0 = w * 8 + lr;
  const int r1 = (4 + w) * 8 + lr;
  const char* ksrc0 = Kc + r0 * 128 + jsw;
  const char* ksrc1 = Kc + r1 * 128 + jsw;
  const char* vsrc0 = Vc + r0 * 4096 + jsw;
  const char* vsrc1 = Vc + r1 * 4096 + jsw;

  bf16x8 qf0, qf1;
  {
    const unsigned short* qp = Q + base + (size_t)(q0 + w * 16 + c) * HD + g * 8;
    qf0 = *(const bf16x8*)qp;
    qf1 = *(const bf16x8*)(qp + 32);
  }
  f32x4 oacc[4] = {};
  float rsum[4] = {0.f, 0.f, 0.f, 0.f};
  unsigned short* pl = &p_lds[w][0];
  const int csw = (c & 7) << 4;

  auto stage = [&](int buf, int t) {
    char* kd = &kbuf[buf][w * 1024 + l * 16];
    char* vd = &vbuf[buf][w * 1024 + l * 16];
    size_t ko = (size_t)t * 8192;
    size_t vo = (size_t)t * 128;
    async_copy16(ksrc0 + ko, kd);
    async_copy16(ksrc1 + ko, kd + 4096);
    async_copy16(vsrc0 + vo, vd);
    async_copy16(vsrc1 + vo, vd + 4096);
  };

  stage(0, p);
  asm volatile("s_waitcnt vmcnt(0)" ::: "memory");
  __syncthreads();
  int cur = 0;

  for (int t = p; t <= qblk; t += 2) {
    if (t + 2 <= qblk) stage(cur ^ 1, t + 2);
    const char* kl = kbuf[cur];
    const char* vl = vbuf[cur];
    const int kv0 = t * 64;

    f32x4 sc[4] = {};
    __builtin_amdgcn_s_setprio(1);
#pragma unroll
    for (int nt = 0; nt < 4; ++nt) {
      bf16x8 k0 = *(const bf16x8*)(kl + (nt * 16 + c) * 128 + ((g * 16) ^ csw));
      bf16x8 k1 = *(const bf16x8*)(kl + (nt * 16 + c) * 128 + ((64 + g * 16) ^ csw));
      sc[nt] = __builtin_amdgcn_mfma_f32_16x16x32_bf16(qf0, k0, sc[nt], 0, 0, 0);
      sc[nt] = __builtin_amdgcn_mfma_f32_16x16x32_bf16(qf1, k1, sc[nt], 0, 0, 0);
    }
    __builtin_amdgcn_s_setprio(0);

    if (t == qblk) {
#pragma unroll
      for (int nt = 0; nt < 4; ++nt)
#pragma unroll
        for (int r = 0; r < 4; ++r) {
          int kvi = kv0 + nt * 16 + c;
          int qi = q0 + w * 16 + 4 * g + r;
          sc[nt][r] = exp2f((kvi > qi) ? -1e30f : sc[nt][r]);
        }
    } else {
#pragma unroll
      for (int nt = 0; nt < 4; ++nt)
#pragma unroll
        for (int r = 0; r < 4; ++r)
          sc[nt][r] = exp2f(sc[nt][r]);
    }
#pragma unroll
    for (int nt = 0; nt < 4; ++nt)
#pragma unroll
      for (int r = 0; r < 4; ++r) {
        float pv = sc[nt][r];
        rsum[r] += pv;
        int row = 4 * g + r, col = nt * 16 + c;
        int byte = row * 128 + ((col * 2) ^ ((row & 7) << 4));
        *(unsigned short*)((char*)pl + byte) = f2bf_fast(pv);
      }
    asm volatile("" ::: "memory");
    __builtin_amdgcn_s_setprio(1);
#pragma unroll
    for (int ks = 0; ks < 2; ++ks) {
      int pbyte = c * 128 + ((ks * 64 + g * 16) ^ csw);
      bf16x8 pf = *(const bf16x8*)((char*)pl + pbyte);
#pragma unroll
      for (int nt = 0; nt < 4; ++nt) {
        bf16x8 vf = *(const bf16x8*)(vl + (nt * 16 + c) * 128 + ((ks * 64 + g * 16) ^ csw));
        oacc[nt] = __builtin_amdgcn_mfma_f32_16x16x32_bf16(pf, vf, oacc[nt], 0, 0, 0);
      }
    }
    __builtin_amdgcn_s_setprio(0);
    asm volatile("" ::: "memory");

    asm volatile("s_waitcnt vmcnt(0)" ::: "memory");
    __syncthreads();
    cur ^= 1;
  }

#pragma unroll
  for (int r = 0; r < 4; ++r) {
    float s = rsum[r];
    s += __shfl_xor(s, 1);
    s += __shfl_xor(s, 2);
    s += __shfl_xor(s, 4);
    s += __shfl_xor(s, 8);
    rsum[r] = s;
  }
  float* pa = part + ((size_t)(bh * 32 + qblk) * 2 + p) * PART_STRIDE;
#pragma unroll
  for (int nt = 0; nt < 4; ++nt)
#pragma unroll
    for (int r = 0; r < 4; ++r) {
      int row = w * 16 + 4 * g + r;
      int col = nt * 16 + c;
      __builtin_nontemporal_store(oacc[nt][r], &pa[row * 64 + col]);
    }
  if (c == 0) {
#pragma unroll
    for (int r = 0; r < 4; ++r) {
      int row = w * 16 + 4 * g + r;
      __builtin_nontemporal_store(rsum[r], &pa[4096 + row]);
    }
  }
}

// ---------------- combine partials -> bf16 attention output [token][h*64+d] ----------------
__global__ __launch_bounds__(256)
void combine_kernel(const float* __restrict__ part, unsigned short* __restrict__ Ob) {
  const int qblk = blockIdx.x & 31;
  const int bh = blockIdx.x >> 5;
  const int b = bh >> 4, h = bh & 15;
  const int tid = threadIdx.x;
  const int row = tid >> 2, colb = (tid & 3) * 16;

  const float* p0 = part + ((size_t)(bh * 32 + qblk) * 2 + 0) * PART_STRIDE;
  const float* p1 = p0 + PART_STRIDE;
  float s0 = __builtin_nontemporal_load(&p0[4096 + row]);
  float s1 = __builtin_nontemporal_load(&p1[4096 + row]);
  float inv = 1.0f / (s0 + s1);

  int token = qblk * 64 + row;
  unsigned short* dst = Ob + ((size_t)b * S_LEN + token) * DM + h * HD + colb;
  const f32x4* a0 = (const f32x4*)(p0 + row * 64 + colb);
  const f32x4* a1 = (const f32x4*)(p1 + row * 64 + colb);
  u16x8 o0, o1;
#pragma unroll
  for (int q = 0; q < 2; ++q) {
    f32x4 v0 = __builtin_nontemporal_load(&a0[2 * q]);
    f32x4 v1 = __builtin_nontemporal_load(&a1[2 * q]);
    f32x4 w0 = __builtin_nontemporal_load(&a0[2 * q + 1]);
    f32x4 w1 = __builtin_nontemporal_load(&a1[2 * q + 1]);
    u16x8& oo = q ? o1 : o0;
    oo[0] = f2bf((v0[0] + v1[0]) * inv);
    oo[1] = f2bf((v0[1] + v1[1]) * inv);
    oo[2] = f2bf((v0[2] + v1[2]) * inv);
    oo[3] = f2bf((v0[3] + v1[3]) * inv);
    oo[4] = f2bf((w0[0] + w1[0]) * inv);
    oo[5] = f2bf((w0[1] + w1[1]) * inv);
    oo[6] = f2bf((w0[2] + w1[2]) * inv);
    oo[7] = f2bf((w0[3] + w1[3]) * inv);
  }
  *(u16x8*)dst = o0;
  *(u16x8*)(dst + 8) = o1;
}

extern "C" void kernel_launch(void* const* d_in, const int* in_sizes, int n_in,
                              void* d_out, int out_size, void* d_ws, size_t ws_size,
                              hipStream_t stream) {
  const float* x = (const float*)d_in[0];
  const int* tpos = (const int*)d_in[1];
  const float* wq = (const float*)d_in[2];
  const float* wk = (const float*)d_in[3];
  const float* wv = (const float*)d_in[4];
  const float* wo = (const float*)d_in[5];
  float* out = (float*)d_out;

  char* ws = (char*)d_ws;
  unsigned short* xb = (unsigned short*)(ws);                          // 4096x1024 bf16
  unsigned short* wqb = (unsigned short*)(ws + 8388608);               // 4x 1024x1024
  unsigned short* wkb = wqb + DM * DM;
  unsigned short* wvb = wqb + 2 * DM * DM;
  unsigned short* wob = wqb + 3 * DM * DM;
  unsigned short* qb = (unsigned short*)(ws + 16777216);               // [b,h,s,d] pre-scaled
  unsigned short* kb = (unsigned short*)(ws + 16777216 + 8388608);     // [b,h,s,d]
  unsigned short* vt = (unsigned short*)(ws + 16777216 + 2 * 8388608); // [b,h,d,s]
  unsigned short* ab = (unsigned short*)(ws + 16777216 + 3 * 8388608); // [t, h*d]
  float2* tab = (float2*)(ws + 50331648);                              // [2048][32] cos/sin
  float* part = (float*)(ws + 50855936);                               // 2048 * 4160 fp32 = 34MB

  cvt_bf16_kernel<<<2048, 256, 0, stream>>>(x, xb, MTOT * DM);
  cvt_w_kernel<<<dim3(512, 4), 256, 0, stream>>>(wq, wk, wv, wo, wqb);
  sincos_tab_kernel<<<256, 256, 0, stream>>>(tpos, tab);

  gemm_qkv_kernel<<<dim3(32, 8, 3), 256, 0, stream>>>(xb, wqb, wkb, wvb, tab, qb, kb, vt);
  attn_kernel<<<2048, 256, 0, stream>>>(qb, kb, vt, part);
  combine_kernel<<<1024, 256, 0, stream>>>(part, ab);
  gemm_out_kernel<<<dim3(32, 8), 256, 0, stream>>>(ab, wob, out);
}

// Round 11
// 126.392 us; speedup vs baseline: 1.1360x; 1.1360x over previous
//
#include <hip/hip_runtime.h>

#define S_LEN 2048
#define NH 16
#define HD 64
#define DM 1024
#define MTOT 4096

// q pre-scale: 1/sqrt(64) * log2(e), so attn softmax is exp2(q.k)
#define QSCALE 0.18033688011112042f

typedef short bf16x8 __attribute__((ext_vector_type(8)));
typedef float f32x4 __attribute__((ext_vector_type(4)));
typedef unsigned short u16x8 __attribute__((ext_vector_type(8)));

__device__ __forceinline__ unsigned short f2bf(float f) {
  unsigned int u = __builtin_bit_cast(unsigned int, f);
  u += 0x7fffu + ((u >> 16) & 1u);
  return (unsigned short)(u >> 16);
}
// round-half-up, 2 ops; bias cancels in softmax normalization
__device__ __forceinline__ unsigned short f2bf_fast(float f) {
  unsigned int u = __builtin_bit_cast(unsigned int, f);
  return (unsigned short)((u + 0x8000u) >> 16);
}

__device__ __forceinline__ void async_copy16(const void* g, void* l) {
  __builtin_amdgcn_global_load_lds(
      (const __attribute__((address_space(1))) unsigned int*)g,
      (__attribute__((address_space(3))) unsigned int*)l, 16, 0, 0);
}

// ---------------- fp32 -> bf16 convert ----------------
__global__ void cvt_bf16_kernel(const float* __restrict__ src,
                                unsigned short* __restrict__ dst, int n) {
  int i = (blockIdx.x * 256 + threadIdx.x) * 8;
  if (i >= n) return;
  const float4* s = (const float4*)(src + i);
  float4 v0 = s[0], v1 = s[1];
  u16x8 o;
  o[0] = f2bf(v0.x); o[1] = f2bf(v0.y); o[2] = f2bf(v0.z); o[3] = f2bf(v0.w);
  o[4] = f2bf(v1.x); o[5] = f2bf(v1.y); o[6] = f2bf(v1.z); o[7] = f2bf(v1.w);
  *(u16x8*)(dst + i) = o;
}

// 4 weight matrices in one launch
__global__ void cvt_w_kernel(const float* __restrict__ w0, const float* __restrict__ w1,
                             const float* __restrict__ w2, const float* __restrict__ w3,
                             unsigned short* __restrict__ dst) {
  int z = blockIdx.y;
  const float* src = (z == 0) ? w0 : (z == 1) ? w1 : (z == 2) ? w2 : w3;
  int i = (blockIdx.x * 256 + threadIdx.x) * 8;
  const float4* s = (const float4*)(src + i);
  float4 v0 = s[0], v1 = s[1];
  u16x8 o;
  o[0] = f2bf(v0.x); o[1] = f2bf(v0.y); o[2] = f2bf(v0.z); o[3] = f2bf(v0.w);
  o[4] = f2bf(v1.x); o[5] = f2bf(v1.y); o[6] = f2bf(v1.z); o[7] = f2bf(v1.w);
  *(u16x8*)(dst + (size_t)z * DM * DM + i) = o;
}

// ---------------- RoPE cos/sin table ----------------
__global__ void sincos_tab_kernel(const int* __restrict__ pos, float2* __restrict__ tab) {
  int idx = blockIdx.x * 256 + threadIdx.x;  // 0 .. 65535
  int s = idx >> 5, i = idx & 31;
  float fr = expf(-(float)i * 0.28782313662425574f);  // ln(10000)/32
  float ang = (float)pos[s] * fr;
  float sn, cs;
  sincosf(ang, &sn, &cs);
  tab[idx] = make_float2(cs, sn);
}

// ---------------- shared GEMM core: C = A(MxK) @ Bt(NxK)^T, 128x128 tile, BK=64 ----------------
// Double-buffered LDS (R9-measured best): stage(next) issued BEFORE compute(cur);
// single vmcnt(0)+barrier per K-step. XOR-swizzled layout (T2): LDS[r][j] = SRC[r][j^(r&7)],
// 16B granules, pre-swizzled source (rule #21: linear dest + inverse-swz source + swz read).
__device__ __forceinline__ void gemm_core(const unsigned short* __restrict__ A,
                                          const unsigned short* __restrict__ Bt,
                                          int m0, int n0, int K,
                                          char* a_lds, char* b_lds,  // each 2 x 16KB
                                          f32x4 (&acc)[4][4]) {
  const int tid = threadIdx.x;
  const int w = tid >> 6, l = tid & 63;
  const int wr = w >> 1, wc = w & 1;
  const int c = l & 15, g = l >> 4;

  const size_t rs = (size_t)K * 2;  // row stride bytes
  const int lr = l >> 3;
  const int jsw = ((l & 7) ^ lr) << 4;  // pre-swizzled source granule
  const char* srcA = (const char*)A + ((size_t)m0 + w * 8 + lr) * rs + jsw;
  const char* srcB = (const char*)Bt + ((size_t)n0 + w * 8 + lr) * rs + jsw;
  char* dstA = a_lds + w * 1024 + l * 16;
  char* dstB = b_lds + w * 1024 + l * 16;
  const int csw = (c & 7) << 4;
  const int nsteps = K / 64;

  auto stage = [&](int buf, int kt) {
    const int off = buf * 16384;
#pragma unroll
    for (int i = 0; i < 4; ++i) {
      async_copy16(srcA + (size_t)i * 32 * rs + kt * 128, dstA + off + i * 4096);
      async_copy16(srcB + (size_t)i * 32 * rs + kt * 128, dstB + off + i * 4096);
    }
  };

  stage(0, 0);
  asm volatile("s_waitcnt vmcnt(0)" ::: "memory");
  __syncthreads();
  int cur = 0;

  for (int kt = 0; kt < nsteps; ++kt) {
    if (kt + 1 < nsteps) stage(cur ^ 1, kt + 1);  // issue next tile early
    const char* al = a_lds + cur * 16384;
    const char* bl = b_lds + cur * 16384;
    __builtin_amdgcn_s_setprio(1);
#pragma unroll
    for (int kk = 0; kk < 2; ++kk) {
      bf16x8 af[4], bfv[4];
#pragma unroll
      for (int mi = 0; mi < 4; ++mi)
        af[mi] = *(const bf16x8*)(al + (wr * 64 + mi * 16 + c) * 128 + ((kk * 64 + g * 16) ^ csw));
#pragma unroll
      for (int ni = 0; ni < 4; ++ni)
        bfv[ni] = *(const bf16x8*)(bl + (wc * 64 + ni * 16 + c) * 128 + ((kk * 64 + g * 16) ^ csw));
#pragma unroll
      for (int mi = 0; mi < 4; ++mi)
#pragma unroll
        for (int ni = 0; ni < 4; ++ni)
          acc[mi][ni] = __builtin_amdgcn_mfma_f32_16x16x32_bf16(af[mi], bfv[ni], acc[mi][ni], 0, 0, 0);
    }
    __builtin_amdgcn_s_setprio(0);
    asm volatile("s_waitcnt vmcnt(0)" ::: "memory");  // next tile landed
    __syncthreads();                                  // all waves done with cur
    cur ^= 1;
  }
}

// ---------------- QKV projection + fused RoPE: q,k -> [b,h,s,d]; v -> [b,h,d,s] ----------------
__global__ __launch_bounds__(256)
void gemm_qkv_kernel(const unsigned short* __restrict__ X,
                     const unsigned short* __restrict__ Wq,
                     const unsigned short* __restrict__ Wk,
                     const unsigned short* __restrict__ Wv,
                     const float2* __restrict__ tab,
                     unsigned short* __restrict__ Qb,
                     unsigned short* __restrict__ Kb,
                     unsigned short* __restrict__ Vt) {
  __shared__ char a_lds[2 * 16384];
  __shared__ char b_lds[2 * 16384];
  const int z = blockIdx.z;
  const unsigned short* Bt = (z == 0) ? Wq : (z == 1) ? Wk : Wv;
  const int m0 = blockIdx.x * 128, n0 = blockIdx.y * 128;

  f32x4 acc[4][4] = {};
  gemm_core(X, Bt, m0, n0, DM, a_lds, b_lds, acc);

  const int tid = threadIdx.x;
  const int w = tid >> 6, l = tid & 63;
  const int wr = w >> 1, wc = w & 1;
  const int c = l & 15, g = l >> 4;

  if (z == 2) {
#pragma unroll
    for (int mi = 0; mi < 4; ++mi)
#pragma unroll
      for (int ni = 0; ni < 4; ++ni)
#pragma unroll
        for (int r = 0; r < 4; ++r) {
          int row = m0 + wr * 64 + mi * 16 + 4 * g + r;  // token
          int col = n0 + wc * 64 + ni * 16 + c;          // feature
          int b = row >> 11, s = row & 2047;
          int h = col >> 6, d = col & 63;
          Vt[((size_t)(b * NH + h) * HD + d) * S_LEN + s] = f2bf(acc[mi][ni][r]);
        }
  } else {
    unsigned short* QK = z ? Kb : Qb;
    const float oscale = z ? 1.0f : QSCALE;
#pragma unroll
    for (int mi = 0; mi < 4; ++mi)
#pragma unroll
      for (int ni = 0; ni < 4; ++ni) {
        int col = n0 + wc * 64 + ni * 16 + c;
        int fi = (col >> 1) & 31;
        float sgn = (col & 1) ? 1.0f : -1.0f;
#pragma unroll
        for (int r = 0; r < 4; ++r) {
          int row = m0 + wr * 64 + mi * 16 + 4 * g + r;
          int b = row >> 11, s = row & 2047;
          float v = acc[mi][ni][r];
          float p = __shfl_xor(v, 1);
          float2 csn = tab[(s << 5) | fi];
          float vr = (v * csn.x + sgn * p * csn.y) * oscale;
          int h = col >> 6, d = col & 63;
          QK[((size_t)(b * NH + h) * S_LEN + s) * HD + d] = f2bf(vr);
        }
      }
  }
}

// ---------------- output projection: fp32 out ----------------
__global__ __launch_bounds__(256)
void gemm_out_kernel(const unsigned short* __restrict__ A,
                     const unsigned short* __restrict__ Wo,
                     float* __restrict__ out) {
  __shared__ char a_lds[2 * 16384];
  __shared__ char b_lds[2 * 16384];
  const int m0 = blockIdx.x * 128, n0 = blockIdx.y * 128;
  f32x4 acc[4][4] = {};
  gemm_core(A, Wo, m0, n0, DM, a_lds, b_lds, acc);

  const int tid = threadIdx.x;
  const int w = tid >> 6, l = tid & 63;
  const int wr = w >> 1, wc = w & 1;
  const int c = l & 15, g = l >> 4;
#pragma unroll
  for (int mi = 0; mi < 4; ++mi)
#pragma unroll
    for (int ni = 0; ni < 4; ++ni)
#pragma unroll
      for (int r = 0; r < 4; ++r) {
        int row = m0 + wr * 64 + mi * 16 + 4 * g + r;
        int col = n0 + wc * 64 + ni * 16 + c;
        out[(size_t)row * DM + col] = acc[mi][ni][r];
      }
}

// ---------------- causal flash attention: LDS-staged double-buffered K/V, no kv-split ----------------
// Block = (bh fastest, qblk permuted {a, 15-a, 16+a, 31-a}): each CU's 4 co-resident blocks
// sum to exactly 66 tile-steps (perfect balance, 40KB LDS -> 4 blocks/CU). Writes bf16 directly.
__global__ __launch_bounds__(256, 4)
void attn_kernel(const unsigned short* __restrict__ Q,
                 const unsigned short* __restrict__ Kb,
                 const unsigned short* __restrict__ Vt,
                 unsigned short* __restrict__ Ob) {
  __shared__ char kbuf[2][8192];
  __shared__ char vbuf[2][8192];
  __shared__ unsigned short p_lds[4][16 * 64];
  const int tid = threadIdx.x;
  const int w = tid >> 6, l = tid & 63;
  const int g = l >> 4, c = l & 15;

  const unsigned int id = blockIdx.x;
  const int bh = id & 31;
  const int j = id >> 5;        // 0..31
  const int a = j & 7, kk = j >> 3;
  const int qblk = (kk == 0) ? a : (kk == 1) ? (15 - a) : (kk == 2) ? (16 + a) : (31 - a);
  const int q0 = qblk * 64;

  const size_t base = (size_t)bh * (S_LEN * HD);
  const char* Kc = (const char*)(Kb + base);
  const char* Vc = (const char*)(Vt + base);

  const int lr = l >> 3;
  const int jsw = ((l & 7) << 4) ^ (lr << 4);
  const int r0 = w * 8 + lr;
  const int r1 = (4 + w) * 8 + lr;
  const char* ksrc0 = Kc + r0 * 128 + jsw;
  const char* ksrc1 = Kc + r1 * 128 + jsw;
  const char* vsrc0 = Vc + r0 * 4096 + jsw;
  const char* vsrc1 = Vc + r1 * 4096 + jsw;

  bf16x8 qf0, qf1;
  {
    const unsigned short* qp = Q + base + (size_t)(q0 + w * 16 + c) * HD + g * 8;
    qf0 = *(const bf16x8*)qp;
    qf1 = *(const bf16x8*)(qp + 32);
  }
  f32x4 oacc[4] = {};
  float rsum[4] = {0.f, 0.f, 0.f, 0.f};
  unsigned short* pl = &p_lds[w][0];
  const int csw = (c & 7) << 4;

  auto stage = [&](int buf, int t) {
    char* kd = &kbuf[buf][w * 1024 + l * 16];
    char* vd = &vbuf[buf][w * 1024 + l * 16];
    size_t ko = (size_t)t * 8192;
    size_t vo = (size_t)t * 128;
    async_copy16(ksrc0 + ko, kd);
    async_copy16(ksrc1 + ko, kd + 4096);
    async_copy16(vsrc0 + vo, vd);
    async_copy16(vsrc1 + vo, vd + 4096);
  };

  stage(0, 0);
  asm volatile("s_waitcnt vmcnt(0)" ::: "memory");
  __syncthreads();
  int cur = 0;

  for (int t = 0; t <= qblk; ++t) {
    if (t + 1 <= qblk) stage(cur ^ 1, t + 1);
    const char* kl = kbuf[cur];
    const char* vl = vbuf[cur];
    const int kv0 = t * 64;

    f32x4 sc[4] = {};
    __builtin_amdgcn_s_setprio(1);
#pragma unroll
    for (int nt = 0; nt < 4; ++nt) {
      bf16x8 k0 = *(const bf16x8*)(kl + (nt * 16 + c) * 128 + ((g * 16) ^ csw));
      bf16x8 k1 = *(const bf16x8*)(kl + (nt * 16 + c) * 128 + ((64 + g * 16) ^ csw));
      sc[nt] = __builtin_amdgcn_mfma_f32_16x16x32_bf16(qf0, k0, sc[nt], 0, 0, 0);
      sc[nt] = __builtin_amdgcn_mfma_f32_16x16x32_bf16(qf1, k1, sc[nt], 0, 0, 0);
    }
    __builtin_amdgcn_s_setprio(0);

    if (t == qblk) {
#pragma unroll
      for (int nt = 0; nt < 4; ++nt)
#pragma unroll
        for (int r = 0; r < 4; ++r) {
          int kvi = kv0 + nt * 16 + c;
          int qi = q0 + w * 16 + 4 * g + r;
          sc[nt][r] = exp2f((kvi > qi) ? -1e30f : sc[nt][r]);
        }
    } else {
#pragma unroll
      for (int nt = 0; nt < 4; ++nt)
#pragma unroll
        for (int r = 0; r < 4; ++r)
          sc[nt][r] = exp2f(sc[nt][r]);
    }
#pragma unroll
    for (int nt = 0; nt < 4; ++nt)
#pragma unroll
      for (int r = 0; r < 4; ++r) {
        float pv = sc[nt][r];
        rsum[r] += pv;
        int row = 4 * g + r, col = nt * 16 + c;
        int byte = row * 128 + ((col * 2) ^ ((row & 7) << 4));
        *(unsigned short*)((char*)pl + byte) = f2bf_fast(pv);
      }
    asm volatile("" ::: "memory");
    __builtin_amdgcn_s_setprio(1);
#pragma unroll
    for (int ks = 0; ks < 2; ++ks) {
      int pbyte = c * 128 + ((ks * 64 + g * 16) ^ csw);
      bf16x8 pf = *(const bf16x8*)((char*)pl + pbyte);
#pragma unroll
      for (int nt = 0; nt < 4; ++nt) {
        bf16x8 vf = *(const bf16x8*)(vl + (nt * 16 + c) * 128 + ((ks * 64 + g * 16) ^ csw));
        oacc[nt] = __builtin_amdgcn_mfma_f32_16x16x32_bf16(pf, vf, oacc[nt], 0, 0, 0);
      }
    }
    __builtin_amdgcn_s_setprio(0);
    asm volatile("" ::: "memory");

    asm volatile("s_waitcnt vmcnt(0)" ::: "memory");  // next tile landed
    __syncthreads();                                  // all waves done with cur
    cur ^= 1;
  }

  // reduce rsum across the 16 col-lanes of each row; write bf16 output directly
#pragma unroll
  for (int r = 0; r < 4; ++r) {
    float s = rsum[r];
    s += __shfl_xor(s, 1);
    s += __shfl_xor(s, 2);
    s += __shfl_xor(s, 4);
    s += __shfl_xor(s, 8);
    rsum[r] = 1.0f / s;
  }
  const int b = bh >> 4, h = bh & 15;
#pragma unroll
  for (int nt = 0; nt < 4; ++nt)
#pragma unroll
    for (int r = 0; r < 4; ++r) {
      int qi = q0 + w * 16 + 4 * g + r;
      int col = nt * 16 + c;
      Ob[((size_t)b * S_LEN + qi) * DM + h * HD + col] = f2bf(oacc[nt][r] * rsum[r]);
    }
}

extern "C" void kernel_launch(void* const* d_in, const int* in_sizes, int n_in,
                              void* d_out, int out_size, void* d_ws, size_t ws_size,
                              hipStream_t stream) {
  const float* x = (const float*)d_in[0];
  const int* tpos = (const int*)d_in[1];
  const float* wq = (const float*)d_in[2];
  const float* wk = (const float*)d_in[3];
  const float* wv = (const float*)d_in[4];
  const float* wo = (const float*)d_in[5];
  float* out = (float*)d_out;

  char* ws = (char*)d_ws;
  unsigned short* xb = (unsigned short*)(ws);                          // 4096x1024 bf16
  unsigned short* wqb = (unsigned short*)(ws + 8388608);               // 4x 1024x1024
  unsigned short* wkb = wqb + DM * DM;
  unsigned short* wvb = wqb + 2 * DM * DM;
  unsigned short* wob = wqb + 3 * DM * DM;
  unsigned short* qb = (unsigned short*)(ws + 16777216);               // [b,h,s,d] pre-scaled
  unsigned short* kb = (unsigned short*)(ws + 16777216 + 8388608);     // [b,h,s,d]
  unsigned short* vt = (unsigned short*)(ws + 16777216 + 2 * 8388608); // [b,h,d,s]
  unsigned short* ab = (unsigned short*)(ws + 16777216 + 3 * 8388608); // [t, h*d]
  float2* tab = (float2*)(ws + 50331648);                              // [2048][32] cos/sin

  cvt_bf16_kernel<<<2048, 256, 0, stream>>>(x, xb, MTOT * DM);
  cvt_w_kernel<<<dim3(512, 4), 256, 0, stream>>>(wq, wk, wv, wo, wqb);
  sincos_tab_kernel<<<256, 256, 0, stream>>>(tpos, tab);

  gemm_qkv_kernel<<<dim3(32, 8, 3), 256, 0, stream>>>(xb, wqb, wkb, wvb, tab, qb, kb, vt);
  attn_kernel<<<1024, 256, 0, stream>>>(qb, kb, vt, ab);
  gemm_out_kernel<<<dim3(32, 8), 256, 0, stream>>>(ab, wob, out);
}